// Round 1
// baseline (1037.079 us; speedup 1.0000x reference)
//
#include <hip/hip_runtime.h>
#include <hip/hip_bf16.h>

#define N_NODES 100000
#define N_EDGES 1600000
#define D_IN 256
#define D_OUT 128

// ---------------- GEMM: h = x @ W  (fp32, vector ALU) ----------------
// 128x128 tile per block, BK=16, 256 threads, 8x8 register tile per thread.
#define BM 128
#define BK 16

__global__ __launch_bounds__(256) void gemm_xw(const float* __restrict__ x,
                                               const float* __restrict__ W,
                                               float* __restrict__ h) {
    __shared__ float xT[BK][BM];     // x tile, transposed: xT[k][row]  (8 KB)
    __shared__ float Wl[BK][D_OUT];  // W tile, row-major              (8 KB)

    const int t  = threadIdx.x;
    const int n0 = blockIdx.x * BM;
    const int rr = t >> 4;   // 0..15  -> rows rr*8 .. rr*8+7
    const int cc = t & 15;   // 0..15  -> cols cc*8 .. cc*8+7

    float acc[8][8];
#pragma unroll
    for (int i = 0; i < 8; ++i)
#pragma unroll
        for (int j = 0; j < 8; ++j) acc[i][j] = 0.f;

    for (int k0 = 0; k0 < D_IN; k0 += BK) {
        // stage x: 128 rows x 16 k  = 2048 floats; each thread 2 float4 loads
#pragma unroll
        for (int pass = 0; pass < 2; ++pass) {
            int row = (t >> 2) + pass * 64;        // 0..127
            int kk  = (t & 3) * 4;                 // 0,4,8,12
            int gr  = n0 + row;
            float4 v = make_float4(0.f, 0.f, 0.f, 0.f);
            if (gr < N_NODES)
                v = *(const float4*)(x + (size_t)gr * D_IN + k0 + kk);
            xT[kk + 0][row] = v.x;
            xT[kk + 1][row] = v.y;
            xT[kk + 2][row] = v.z;
            xT[kk + 3][row] = v.w;
        }
        // stage W: 16 k-rows x 128 cols = 2048 floats
#pragma unroll
        for (int pass = 0; pass < 2; ++pass) {
            int kr  = (t >> 5) + pass * 8;         // 0..15
            int col = (t & 31) * 4;                // 0..124
            float4 v = *(const float4*)(W + (size_t)(k0 + kr) * D_OUT + col);
            *(float4*)&Wl[kr][col] = v;
        }
        __syncthreads();

#pragma unroll
        for (int k = 0; k < BK; ++k) {
            float a[8], b[8];
            *(float4*)&a[0] = *(const float4*)&xT[k][rr * 8];
            *(float4*)&a[4] = *(const float4*)&xT[k][rr * 8 + 4];
            *(float4*)&b[0] = *(const float4*)&Wl[k][cc * 8];
            *(float4*)&b[4] = *(const float4*)&Wl[k][cc * 8 + 4];
#pragma unroll
            for (int i = 0; i < 8; ++i)
#pragma unroll
                for (int j = 0; j < 8; ++j) acc[i][j] += a[i] * b[j];
        }
        __syncthreads();
    }

    // epilogue
#pragma unroll
    for (int i = 0; i < 8; ++i) {
        int gr = n0 + rr * 8 + i;
        if (gr < N_NODES) {
            float4 v0 = make_float4(acc[i][0], acc[i][1], acc[i][2], acc[i][3]);
            float4 v1 = make_float4(acc[i][4], acc[i][5], acc[i][6], acc[i][7]);
            *(float4*)(h + (size_t)gr * D_OUT + cc * 8)     = v0;
            *(float4*)(h + (size_t)gr * D_OUT + cc * 8 + 4) = v1;
        }
    }
}

// ------------- Scatter: out[r] += v * h[c]  (atomic, fp32) -------------
// one thread per (edge, dim); wave = 64 consecutive dims of one edge.
__global__ __launch_bounds__(256) void scatter_edges(const int* __restrict__ rows,
                                                     const int* __restrict__ cols,
                                                     const float* __restrict__ vals,
                                                     const float* __restrict__ h,
                                                     float* __restrict__ out) {
    size_t idx = (size_t)blockIdx.x * 256 + threadIdx.x;
    int e = (int)(idx >> 7);
    int d = (int)(idx & 127);
    float v = vals[e];
    int   c = cols[e];
    int   r = rows[e];
    float m = v * h[(size_t)c * D_OUT + d];
    atomicAdd(out + (size_t)r * D_OUT + d, m);
}

// --------------------------- ReLU in place ---------------------------
__global__ __launch_bounds__(256) void relu_inplace(float* __restrict__ out, int n) {
    int i = blockIdx.x * 256 + threadIdx.x;
    if (i < n) {
        float v = out[i];
        out[i] = v > 0.f ? v : 0.f;
    }
}

extern "C" void kernel_launch(void* const* d_in, const int* in_sizes, int n_in,
                              void* d_out, int out_size, void* d_ws, size_t ws_size,
                              hipStream_t stream) {
    const float* x    = (const float*)d_in[0];
    const float* W    = (const float*)d_in[1];
    const int*   rows = (const int*)d_in[2];
    const int*   cols = (const int*)d_in[3];
    const float* vals = (const float*)d_in[4];
    float* out = (float*)d_out;
    float* h   = (float*)d_ws;   // N_NODES * D_OUT floats = 51.2 MB

    // harness re-poisons d_out to 0xAA before every timed call -> zero it
    hipMemsetAsync(d_out, 0, (size_t)out_size * sizeof(float), stream);

    // h = x @ W
    int gemm_blocks = (N_NODES + BM - 1) / BM;  // 782
    gemm_xw<<<gemm_blocks, 256, 0, stream>>>(x, W, h);

    // out[r] += v * h[c]
    size_t total = (size_t)N_EDGES * D_OUT;          // 204.8M
    int sc_blocks = (int)(total / 256);              // exact multiple
    scatter_edges<<<sc_blocks, 256, 0, stream>>>(rows, cols, vals, h, out);

    // relu
    int rl_blocks = (out_size + 255) / 256;
    relu_inplace<<<rl_blocks, 256, 0, stream>>>(out, out_size);
}

// Round 2
// 801.935 us; speedup vs baseline: 1.2932x; 1.2932x over previous
//
#include <hip/hip_runtime.h>
#include <hip/hip_bf16.h>

#define N_NODES 100000
#define N_EDGES 1600000
#define D_IN 256
#define D_OUT 128

// ---------------- GEMM: h = x @ W  (fp32, vector ALU) ----------------
#define BM 128
#define BK 16

__global__ __launch_bounds__(256) void gemm_xw(const float* __restrict__ x,
                                               const float* __restrict__ W,
                                               float* __restrict__ h) {
    __shared__ float xT[BK][BM];     // x tile, transposed: xT[k][row]
    __shared__ float Wl[BK][D_OUT];  // W tile, row-major

    const int t  = threadIdx.x;
    const int n0 = blockIdx.x * BM;
    const int rr = t >> 4;   // 0..15
    const int cc = t & 15;   // 0..15

    float acc[8][8];
#pragma unroll
    for (int i = 0; i < 8; ++i)
#pragma unroll
        for (int j = 0; j < 8; ++j) acc[i][j] = 0.f;

    for (int k0 = 0; k0 < D_IN; k0 += BK) {
#pragma unroll
        for (int pass = 0; pass < 2; ++pass) {
            int row = (t >> 2) + pass * 64;
            int kk  = (t & 3) * 4;
            int gr  = n0 + row;
            float4 v = make_float4(0.f, 0.f, 0.f, 0.f);
            if (gr < N_NODES)
                v = *(const float4*)(x + (size_t)gr * D_IN + k0 + kk);
            xT[kk + 0][row] = v.x;
            xT[kk + 1][row] = v.y;
            xT[kk + 2][row] = v.z;
            xT[kk + 3][row] = v.w;
        }
#pragma unroll
        for (int pass = 0; pass < 2; ++pass) {
            int kr  = (t >> 5) + pass * 8;
            int col = (t & 31) * 4;
            float4 v = *(const float4*)(W + (size_t)(k0 + kr) * D_OUT + col);
            *(float4*)&Wl[kr][col] = v;
        }
        __syncthreads();

#pragma unroll
        for (int k = 0; k < BK; ++k) {
            float a[8], b[8];
            *(float4*)&a[0] = *(const float4*)&xT[k][rr * 8];
            *(float4*)&a[4] = *(const float4*)&xT[k][rr * 8 + 4];
            *(float4*)&b[0] = *(const float4*)&Wl[k][cc * 8];
            *(float4*)&b[4] = *(const float4*)&Wl[k][cc * 8 + 4];
#pragma unroll
            for (int i = 0; i < 8; ++i)
#pragma unroll
                for (int j = 0; j < 8; ++j) acc[i][j] += a[i] * b[j];
        }
        __syncthreads();
    }

#pragma unroll
    for (int i = 0; i < 8; ++i) {
        int gr = n0 + rr * 8 + i;
        if (gr < N_NODES) {
            float4 v0 = make_float4(acc[i][0], acc[i][1], acc[i][2], acc[i][3]);
            float4 v1 = make_float4(acc[i][4], acc[i][5], acc[i][6], acc[i][7]);
            *(float4*)(h + (size_t)gr * D_OUT + cc * 8)     = v0;
            *(float4*)(h + (size_t)gr * D_OUT + cc * 8 + 4) = v1;
        }
    }
}

// ---------------- CSR build ----------------
// counts/cursor share one buffer: hist writes counts; scan converts in place
// to exclusive offsets (cursor) and also writes ptr.

__global__ __launch_bounds__(256) void hist_rows(const int* __restrict__ rows,
                                                 int* __restrict__ counts) {
    int e = blockIdx.x * 256 + threadIdx.x;
    if (e < N_EDGES) atomicAdd(&counts[rows[e]], 1);
}

// single block, 1024 threads: exclusive scan of counts[n] -> ptr[n+1], cursor[n]
__global__ __launch_bounds__(1024) void scan_counts(int* __restrict__ counts_cursor,
                                                    int* __restrict__ ptr, int n) {
    __shared__ int wtot[16];
    __shared__ int s_carry;
    __shared__ int s_chunk;
    const int t    = threadIdx.x;
    const int lane = t & 63;
    const int wid  = t >> 6;
    if (t == 0) s_carry = 0;
    __syncthreads();

    for (int base = 0; base < n; base += 1024) {
        int i = base + t;
        int v = (i < n) ? counts_cursor[i] : 0;
        // wave-inclusive scan
        int x = v;
#pragma unroll
        for (int off = 1; off < 64; off <<= 1) {
            int u = __shfl_up(x, off);
            if (lane >= off) x += u;
        }
        if (lane == 63) wtot[wid] = x;
        __syncthreads();
        if (wid == 0) {
            int wv = (lane < 16) ? wtot[lane] : 0;
            int y = wv;
#pragma unroll
            for (int off = 1; off < 16; off <<= 1) {
                int u = __shfl_up(y, off);
                if (lane >= off) y += u;
            }
            if (lane < 16) wtot[lane] = y - wv;  // exclusive wave offset
            if (lane == 15) s_chunk = y;         // chunk total
        }
        __syncthreads();
        int excl = (x - v) + wtot[wid] + s_carry;
        if (i < n) {
            ptr[i] = excl;
            counts_cursor[i] = excl;  // cursor for permute
        }
        __syncthreads();
        if (t == 0) s_carry += s_chunk;
        __syncthreads();
    }
    if (t == 0) ptr[n] = s_carry;
}

__global__ __launch_bounds__(256) void permute_edges(const int* __restrict__ rows,
                                                     int* __restrict__ cursor,
                                                     int* __restrict__ perm) {
    int e = blockIdx.x * 256 + threadIdx.x;
    if (e < N_EDGES) {
        int r = rows[e];
        int pos = atomicAdd(&cursor[r], 1);
        perm[pos] = e;
    }
}

// ---------------- Gather: out[r] = relu(sum v*h[c]) ----------------
// one wave per row; lane handles 2 dims via float2. 4 rows per 256-block.
__global__ __launch_bounds__(256) void gather_rows(const int* __restrict__ ptr,
                                                   const int* __restrict__ perm,
                                                   const int* __restrict__ cols,
                                                   const float* __restrict__ vals,
                                                   const float* __restrict__ h,
                                                   float* __restrict__ out) {
    int row  = blockIdx.x * 4 + (threadIdx.x >> 6);
    int lane = threadIdx.x & 63;
    if (row >= N_NODES) return;
    int beg = ptr[row], end = ptr[row + 1];
    float2 acc = make_float2(0.f, 0.f);
    int e_next = (beg < end) ? perm[beg] : 0;
    for (int j = beg; j < end; ++j) {
        int e = e_next;
        if (j + 1 < end) e_next = perm[j + 1];
        int c   = cols[e];
        float v = vals[e];
        float2 hv = *(const float2*)(h + (size_t)c * D_OUT + lane * 2);
        acc.x += v * hv.x;
        acc.y += v * hv.y;
    }
    acc.x = fmaxf(acc.x, 0.f);
    acc.y = fmaxf(acc.y, 0.f);
    *(float2*)(out + (size_t)row * D_OUT + lane * 2) = acc;
}

// ---------------- fallback path (atomic scatter) ----------------
__global__ __launch_bounds__(256) void scatter_edges(const int* __restrict__ rows,
                                                     const int* __restrict__ cols,
                                                     const float* __restrict__ vals,
                                                     const float* __restrict__ h,
                                                     float* __restrict__ out) {
    size_t idx = (size_t)blockIdx.x * 256 + threadIdx.x;
    int e = (int)(idx >> 7);
    int d = (int)(idx & 127);
    float v = vals[e];
    int   c = cols[e];
    int   r = rows[e];
    float m = v * h[(size_t)c * D_OUT + d];
    atomicAdd(out + (size_t)r * D_OUT + d, m);
}

__global__ __launch_bounds__(256) void relu_inplace(float* __restrict__ out, int n) {
    int i = blockIdx.x * 256 + threadIdx.x;
    if (i < n) {
        float v = out[i];
        out[i] = v > 0.f ? v : 0.f;
    }
}

extern "C" void kernel_launch(void* const* d_in, const int* in_sizes, int n_in,
                              void* d_out, int out_size, void* d_ws, size_t ws_size,
                              hipStream_t stream) {
    const float* x    = (const float*)d_in[0];
    const float* W    = (const float*)d_in[1];
    const int*   rows = (const int*)d_in[2];
    const int*   cols = (const int*)d_in[3];
    const float* vals = (const float*)d_in[4];
    float* out = (float*)d_out;

    // workspace layout
    char* ws = (char*)d_ws;
    const size_t h_bytes      = (size_t)N_NODES * D_OUT * sizeof(float);  // 51.2 MB
    const size_t ptr_bytes    = (size_t)(N_NODES + 1) * sizeof(int);
    const size_t cursor_bytes = (size_t)N_NODES * sizeof(int);
    const size_t perm_bytes   = (size_t)N_EDGES * sizeof(int);
    size_t off = 0;
    float* h = (float*)(ws + off); off += (h_bytes + 255) & ~(size_t)255;
    int* ptr    = (int*)(ws + off); off += (ptr_bytes + 255) & ~(size_t)255;
    int* cursor = (int*)(ws + off); off += (cursor_bytes + 255) & ~(size_t)255;
    int* perm   = (int*)(ws + off); off += (perm_bytes + 255) & ~(size_t)255;
    const bool csr_ok = (off <= ws_size);

    // h = x @ W
    int gemm_blocks = (N_NODES + BM - 1) / BM;
    gemm_xw<<<gemm_blocks, 256, 0, stream>>>(x, W, h);

    if (csr_ok) {
        // zero counters (cursor buffer doubles as counts)
        hipMemsetAsync(cursor, 0, cursor_bytes, stream);
        int eb = (N_EDGES + 255) / 256;
        hist_rows<<<eb, 256, 0, stream>>>(rows, cursor);
        scan_counts<<<1, 1024, 0, stream>>>(cursor, ptr, N_NODES);
        permute_edges<<<eb, 256, 0, stream>>>(rows, cursor, perm);
        int gb = (N_NODES + 3) / 4;
        gather_rows<<<gb, 256, 0, stream>>>(ptr, perm, cols, vals, h, out);
    } else {
        hipMemsetAsync(d_out, 0, (size_t)out_size * sizeof(float), stream);
        size_t total = (size_t)N_EDGES * D_OUT;
        int sc_blocks = (int)(total / 256);
        scatter_edges<<<sc_blocks, 256, 0, stream>>>(rows, cols, vals, h, out);
        int rl_blocks = (out_size + 255) / 256;
        relu_inplace<<<rl_blocks, 256, 0, stream>>>(out, out_size);
    }
}

// Round 3
// 526.569 us; speedup vs baseline: 1.9695x; 1.5229x over previous
//
#include <hip/hip_runtime.h>
#include <hip/hip_bf16.h>

#define N_NODES 100000
#define N_EDGES 1600000
#define D_IN 256
#define D_OUT 128

typedef short bf16x8 __attribute__((ext_vector_type(8)));
typedef float f32x4 __attribute__((ext_vector_type(4)));

__device__ __forceinline__ unsigned short f2bf(float f) {
    unsigned int u = __builtin_bit_cast(unsigned int, f);
    u += 0x7fffu + ((u >> 16) & 1u);   // round-to-nearest-even
    return (unsigned short)(u >> 16);
}

// ---------- W transpose+convert: WbT[n][k] = bf16(W[k][n]) ----------
__global__ __launch_bounds__(256) void convert_w(const float* __restrict__ W,
                                                 unsigned short* __restrict__ WbT) {
    int i = blockIdx.x * 256 + threadIdx.x;      // 32768 total
    int k = i >> 7;                              // 0..255
    int n = i & 127;                             // 0..127
    WbT[(size_t)n * D_IN + k] = f2bf(W[i]);
}

// ---------- GEMM: hb = bf16(x @ W), MFMA 16x16x32, no LDS ----------
// block = 4 waves, each wave does 16 rows x 128 cols; K=256 in 8 chunks.
__global__ __launch_bounds__(256) void gemm_mfma(const float* __restrict__ x,
                                                 const unsigned short* __restrict__ WbT,
                                                 unsigned short* __restrict__ hb) {
    const int wave = threadIdx.x >> 6;
    const int lane = threadIdx.x & 63;
    const int row0 = blockIdx.x * 64 + wave * 16;
    if (row0 >= N_NODES) return;                 // wave-uniform (100000 % 16 == 0)
    const int m = lane & 15;
    const int q = lane >> 4;

    const float* xrow = x + (size_t)(row0 + m) * D_IN;

    f32x4 acc[8];
#pragma unroll
    for (int nt = 0; nt < 8; ++nt) acc[nt] = (f32x4){0.f, 0.f, 0.f, 0.f};

#pragma unroll
    for (int kc = 0; kc < 8; ++kc) {
        const int kb = kc * 32 + q * 8;
        float4 a0 = *(const float4*)(xrow + kb);
        float4 a1 = *(const float4*)(xrow + kb + 4);
        bf16x8 af;
        af[0] = (short)f2bf(a0.x); af[1] = (short)f2bf(a0.y);
        af[2] = (short)f2bf(a0.z); af[3] = (short)f2bf(a0.w);
        af[4] = (short)f2bf(a1.x); af[5] = (short)f2bf(a1.y);
        af[6] = (short)f2bf(a1.z); af[7] = (short)f2bf(a1.w);
#pragma unroll
        for (int nt = 0; nt < 8; ++nt) {
            bf16x8 bf = *(const bf16x8*)(WbT + (size_t)(nt * 16 + m) * D_IN + kb);
            acc[nt] = __builtin_amdgcn_mfma_f32_16x16x32_bf16(af, bf, acc[nt], 0, 0, 0);
        }
    }

    // D: row = q*4 + r, col = nt*16 + m
#pragma unroll
    for (int nt = 0; nt < 8; ++nt) {
#pragma unroll
        for (int r = 0; r < 4; ++r) {
            int grow = row0 + q * 4 + r;
            hb[(size_t)grow * D_OUT + nt * 16 + m] = f2bf(acc[nt][r]);
        }
    }
}

// ---------- histogram of rows (4 edges/thread) ----------
__global__ __launch_bounds__(256) void hist_rows(const int* __restrict__ rows,
                                                 int* __restrict__ counts) {
    int i = blockIdx.x * 256 + threadIdx.x;      // over N_EDGES/4
    if (i < N_EDGES / 4) {
        int4 r = *(const int4*)(rows + i * 4);
        atomicAdd(&counts[r.x], 1);
        atomicAdd(&counts[r.y], 1);
        atomicAdd(&counts[r.z], 1);
        atomicAdd(&counts[r.w], 1);
    }
}

// ---------- hierarchical scan: reduce -> scan partials -> apply ----------
#define SCHUNK 1024
__global__ __launch_bounds__(1024) void scan_reduce(const int* __restrict__ counts,
                                                    int* __restrict__ bsum, int n) {
    __shared__ int ws[16];
    const int t = threadIdx.x, lane = t & 63, wid = t >> 6;
    int i = blockIdx.x * SCHUNK + t;
    int v = (i < n) ? counts[i] : 0;
#pragma unroll
    for (int off = 32; off >= 1; off >>= 1) v += __shfl_down(v, off);
    if (lane == 0) ws[wid] = v;
    __syncthreads();
    if (t == 0) {
        int s = 0;
#pragma unroll
        for (int w = 0; w < 16; ++w) s += ws[w];
        bsum[blockIdx.x] = s;
    }
}

__global__ __launch_bounds__(64) void scan_bsums(int* __restrict__ bsum, int nb) {
    const int lane = threadIdx.x;
    int carry = 0;
    for (int base = 0; base < nb; base += 64) {
        int i = base + lane;
        int v = (i < nb) ? bsum[i] : 0;
        int x = v;
#pragma unroll
        for (int off = 1; off < 64; off <<= 1) {
            int u = __shfl_up(x, off);
            if (lane >= off) x += u;
        }
        if (i < nb) bsum[i] = x - v + carry;
        carry += __shfl(x, 63);
    }
}

__global__ __launch_bounds__(1024) void scan_apply(const int* __restrict__ counts,
                                                   const int* __restrict__ bsum,
                                                   int* __restrict__ ptr,
                                                   int* __restrict__ cursor, int n) {
    __shared__ int wtot[16];
    const int t = threadIdx.x, lane = t & 63, wid = t >> 6;
    int i = blockIdx.x * SCHUNK + t;
    int v = (i < n) ? counts[i] : 0;
    int x = v;
#pragma unroll
    for (int off = 1; off < 64; off <<= 1) {
        int u = __shfl_up(x, off);
        if (lane >= off) x += u;
    }
    if (lane == 63) wtot[wid] = x;
    __syncthreads();
    if (wid == 0) {
        int wv = (lane < 16) ? wtot[lane] : 0;
        int y = wv;
#pragma unroll
        for (int off = 1; off < 16; off <<= 1) {
            int u = __shfl_up(y, off);
            if (lane >= off) y += u;
        }
        if (lane < 16) wtot[lane] = y - wv;
    }
    __syncthreads();
    int excl = (x - v) + wtot[wid] + bsum[blockIdx.x];
    if (i < n) {
        ptr[i] = excl;
        cursor[i] = excl;
        if (i == n - 1) ptr[n] = excl + v;
    }
}

// ---------- permute: write row-sorted cols/vals directly ----------
__global__ __launch_bounds__(256) void permute_edges(const int* __restrict__ rows,
                                                     const int* __restrict__ cols,
                                                     const float* __restrict__ vals,
                                                     int* __restrict__ cursor,
                                                     int* __restrict__ col_r,
                                                     float* __restrict__ val_r) {
    int e = blockIdx.x * 256 + threadIdx.x;
    if (e < N_EDGES) {
        int r = rows[e];
        int pos = atomicAdd(&cursor[r], 1);
        col_r[pos] = cols[e];
        val_r[pos] = vals[e];
    }
}

// ---------- gather: out[row] = relu(sum v * hb[c]) ----------
// one wave per row; lane owns 2 dims (one u32 = 2 bf16).
__global__ __launch_bounds__(256) void gather_rows(const int* __restrict__ ptr,
                                                   const int* __restrict__ col_r,
                                                   const float* __restrict__ val_r,
                                                   const unsigned short* __restrict__ hb,
                                                   float* __restrict__ out) {
    int row  = blockIdx.x * 4 + (threadIdx.x >> 6);
    int lane = threadIdx.x & 63;
    if (row >= N_NODES) return;
    int beg = ptr[row], end = ptr[row + 1];
    float accx = 0.f, accy = 0.f;
    int   c_nx = 0; float v_nx = 0.f;
    if (beg < end) { c_nx = col_r[beg]; v_nx = val_r[beg]; }
    for (int j = beg; j < end; ++j) {
        int c = c_nx; float v = v_nx;
        if (j + 1 < end) { c_nx = col_r[j + 1]; v_nx = val_r[j + 1]; }
        unsigned int hv = *(const unsigned int*)(hb + (size_t)c * D_OUT + lane * 2);
        float f0 = __builtin_bit_cast(float, hv << 16);
        float f1 = __builtin_bit_cast(float, hv & 0xffff0000u);
        accx = fmaf(v, f0, accx);
        accy = fmaf(v, f1, accy);
    }
    float2 o = make_float2(fmaxf(accx, 0.f), fmaxf(accy, 0.f));
    *(float2*)(out + (size_t)row * D_OUT + lane * 2) = o;
}

extern "C" void kernel_launch(void* const* d_in, const int* in_sizes, int n_in,
                              void* d_out, int out_size, void* d_ws, size_t ws_size,
                              hipStream_t stream) {
    const float* x    = (const float*)d_in[0];
    const float* W    = (const float*)d_in[1];
    const int*   rows = (const int*)d_in[2];
    const int*   cols = (const int*)d_in[3];
    const float* vals = (const float*)d_in[4];
    float* out = (float*)d_out;

    // workspace layout (~39.3 MB; ws proven >= 58.4 MB in round 2)
    char* ws = (char*)d_ws;
    size_t off = 0;
    unsigned short* hb  = (unsigned short*)(ws + off); off += ((size_t)N_NODES * D_OUT * 2 + 255) & ~(size_t)255;
    unsigned short* WbT = (unsigned short*)(ws + off); off += ((size_t)D_IN * D_OUT * 2 + 255) & ~(size_t)255;
    int*   ptr    = (int*)(ws + off); off += ((size_t)(N_NODES + 1) * 4 + 255) & ~(size_t)255;
    int*   cursor = (int*)(ws + off); off += ((size_t)N_NODES * 4 + 255) & ~(size_t)255;
    int*   col_r  = (int*)(ws + off); off += ((size_t)N_EDGES * 4 + 255) & ~(size_t)255;
    float* val_r  = (float*)(ws + off); off += ((size_t)N_EDGES * 4 + 255) & ~(size_t)255;
    int*   bsum   = (int*)(ws + off); off += 4096;

    const int nscan = (N_NODES + SCHUNK - 1) / SCHUNK;  // 98

    convert_w<<<(D_IN * D_OUT) / 256, 256, 0, stream>>>(W, WbT);
    gemm_mfma<<<(N_NODES + 63) / 64, 256, 0, stream>>>(x, WbT, hb);

    hipMemsetAsync(cursor, 0, (size_t)N_NODES * 4, stream);
    hist_rows<<<(N_EDGES / 4 + 255) / 256, 256, 0, stream>>>(rows, cursor);
    scan_reduce<<<nscan, 1024, 0, stream>>>(cursor, bsum, N_NODES);
    scan_bsums<<<1, 64, 0, stream>>>(bsum, nscan);
    scan_apply<<<nscan, 1024, 0, stream>>>(cursor, bsum, ptr, cursor, N_NODES);
    permute_edges<<<(N_EDGES + 255) / 256, 256, 0, stream>>>(rows, cols, vals, cursor, col_r, val_r);

    gather_rows<<<(N_NODES + 3) / 4, 256, 0, stream>>>(ptr, col_r, val_r, hb, out);
}

// Round 4
// 452.201 us; speedup vs baseline: 2.2934x; 1.1645x over previous
//
#include <hip/hip_runtime.h>
#include <hip/hip_bf16.h>

#define N_NODES 100000
#define N_EDGES 1600000
#define D_IN 256
#define D_OUT 128

typedef short bf16x8 __attribute__((ext_vector_type(8)));
typedef float f32x4 __attribute__((ext_vector_type(4)));

__device__ __forceinline__ unsigned short f2bf(float f) {
    unsigned int u = __builtin_bit_cast(unsigned int, f);
    u += 0x7fffu + ((u >> 16) & 1u);   // round-to-nearest-even
    return (unsigned short)(u >> 16);
}
__device__ __forceinline__ float bf_lo(unsigned int h) {
    return __builtin_bit_cast(float, h << 16);
}
__device__ __forceinline__ float bf_hi(unsigned int h) {
    return __builtin_bit_cast(float, h & 0xffff0000u);
}

// ---------- W transpose+convert: WbT[n][k] = bf16(W[k][n]) ----------
__global__ __launch_bounds__(256) void convert_w(const float* __restrict__ W,
                                                 unsigned short* __restrict__ WbT) {
    int i = blockIdx.x * 256 + threadIdx.x;      // 32768 total
    int k = i >> 7;
    int n = i & 127;
    WbT[(size_t)n * D_IN + k] = f2bf(W[i]);
}

// ---------- GEMM: hb = bf16(x @ W), MFMA 16x16x32 ----------
// wave does 32 rows x 128 cols (two A-frags share every B-frag).
__global__ __launch_bounds__(256) void gemm_mfma(const float* __restrict__ x,
                                                 const unsigned short* __restrict__ WbT,
                                                 unsigned short* __restrict__ hb) {
    const int wave = threadIdx.x >> 6;
    const int lane = threadIdx.x & 63;
    const int row0 = blockIdx.x * 128 + wave * 32;
    if (row0 >= N_NODES) return;                 // wave-uniform (100000 % 32 == 0)
    const int m = lane & 15;
    const int q = lane >> 4;

    const float* xr0 = x + (size_t)(row0 + m) * D_IN;
    const float* xr1 = x + (size_t)(row0 + 16 + m) * D_IN;

    f32x4 acc[2][8];
#pragma unroll
    for (int h = 0; h < 2; ++h)
#pragma unroll
        for (int nt = 0; nt < 8; ++nt) acc[h][nt] = (f32x4){0.f, 0.f, 0.f, 0.f};

#pragma unroll
    for (int kc = 0; kc < 8; ++kc) {
        const int kb = kc * 32 + q * 8;
        float4 a00 = *(const float4*)(xr0 + kb);
        float4 a01 = *(const float4*)(xr0 + kb + 4);
        float4 a10 = *(const float4*)(xr1 + kb);
        float4 a11 = *(const float4*)(xr1 + kb + 4);
        bf16x8 af0, af1;
        af0[0] = (short)f2bf(a00.x); af0[1] = (short)f2bf(a00.y);
        af0[2] = (short)f2bf(a00.z); af0[3] = (short)f2bf(a00.w);
        af0[4] = (short)f2bf(a01.x); af0[5] = (short)f2bf(a01.y);
        af0[6] = (short)f2bf(a01.z); af0[7] = (short)f2bf(a01.w);
        af1[0] = (short)f2bf(a10.x); af1[1] = (short)f2bf(a10.y);
        af1[2] = (short)f2bf(a10.z); af1[3] = (short)f2bf(a10.w);
        af1[4] = (short)f2bf(a11.x); af1[5] = (short)f2bf(a11.y);
        af1[6] = (short)f2bf(a11.z); af1[7] = (short)f2bf(a11.w);
#pragma unroll
        for (int nt = 0; nt < 8; ++nt) {
            bf16x8 bf = *(const bf16x8*)(WbT + (size_t)(nt * 16 + m) * D_IN + kb);
            acc[0][nt] = __builtin_amdgcn_mfma_f32_16x16x32_bf16(af0, bf, acc[0][nt], 0, 0, 0);
            acc[1][nt] = __builtin_amdgcn_mfma_f32_16x16x32_bf16(af1, bf, acc[1][nt], 0, 0, 0);
        }
    }

    // D layout: row = q*4 + r, col = nt*16 + m
#pragma unroll
    for (int h = 0; h < 2; ++h)
#pragma unroll
        for (int nt = 0; nt < 8; ++nt)
#pragma unroll
            for (int r = 0; r < 4; ++r) {
                int grow = row0 + h * 16 + q * 4 + r;
                hb[(size_t)grow * D_OUT + nt * 16 + m] = f2bf(acc[h][nt][r]);
            }
}

// ---------- histogram of rows ----------
__global__ __launch_bounds__(256) void hist_rows(const int* __restrict__ rows,
                                                 int* __restrict__ counts) {
    int i = blockIdx.x * 256 + threadIdx.x;
    if (i < N_EDGES / 4) {
        int4 r = *(const int4*)(rows + i * 4);
        atomicAdd(&counts[r.x], 1);
        atomicAdd(&counts[r.y], 1);
        atomicAdd(&counts[r.z], 1);
        atomicAdd(&counts[r.w], 1);
    }
}

// ---------- hierarchical scan ----------
#define SCHUNK 1024
__global__ __launch_bounds__(1024) void scan_reduce(const int* __restrict__ counts,
                                                    int* __restrict__ bsum, int n) {
    __shared__ int ws[16];
    const int t = threadIdx.x, lane = t & 63, wid = t >> 6;
    int i = blockIdx.x * SCHUNK + t;
    int v = (i < n) ? counts[i] : 0;
#pragma unroll
    for (int off = 32; off >= 1; off >>= 1) v += __shfl_down(v, off);
    if (lane == 0) ws[wid] = v;
    __syncthreads();
    if (t == 0) {
        int s = 0;
#pragma unroll
        for (int w = 0; w < 16; ++w) s += ws[w];
        bsum[blockIdx.x] = s;
    }
}

__global__ __launch_bounds__(64) void scan_bsums(int* __restrict__ bsum, int nb) {
    const int lane = threadIdx.x;
    int carry = 0;
    for (int base = 0; base < nb; base += 64) {
        int i = base + lane;
        int v = (i < nb) ? bsum[i] : 0;
        int x = v;
#pragma unroll
        for (int off = 1; off < 64; off <<= 1) {
            int u = __shfl_up(x, off);
            if (lane >= off) x += u;
        }
        if (i < nb) bsum[i] = x - v + carry;
        carry += __shfl(x, 63);
    }
}

__global__ __launch_bounds__(1024) void scan_apply(const int* __restrict__ counts,
                                                   const int* __restrict__ bsum,
                                                   int* __restrict__ ptr,
                                                   int* __restrict__ cursor, int n) {
    __shared__ int wtot[16];
    const int t = threadIdx.x, lane = t & 63, wid = t >> 6;
    int i = blockIdx.x * SCHUNK + t;
    int v = (i < n) ? counts[i] : 0;
    int x = v;
#pragma unroll
    for (int off = 1; off < 64; off <<= 1) {
        int u = __shfl_up(x, off);
        if (lane >= off) x += u;
    }
    if (lane == 63) wtot[wid] = x;
    __syncthreads();
    if (wid == 0) {
        int wv = (lane < 16) ? wtot[lane] : 0;
        int y = wv;
#pragma unroll
        for (int off = 1; off < 16; off <<= 1) {
            int u = __shfl_up(y, off);
            if (lane >= off) y += u;
        }
        if (lane < 16) wtot[lane] = y - wv;
    }
    __syncthreads();
    int excl = (x - v) + wtot[wid] + bsum[blockIdx.x];
    if (i < n) {
        ptr[i] = excl;
        cursor[i] = excl;
        if (i == n - 1) ptr[n] = excl + v;
    }
}

// ---------- permute: packed (col, val) single 8B random store per edge ----------
__global__ __launch_bounds__(256) void permute_edges(const int* __restrict__ rows,
                                                     const int* __restrict__ cols,
                                                     const float* __restrict__ vals,
                                                     int* __restrict__ cursor,
                                                     int2* __restrict__ edge_r) {
    int i = blockIdx.x * 256 + threadIdx.x;
    if (i < N_EDGES / 4) {
        int4   r = *(const int4*)(rows + i * 4);
        int4   c = *(const int4*)(cols + i * 4);
        float4 v = *(const float4*)(vals + i * 4);
        int p0 = atomicAdd(&cursor[r.x], 1);
        int p1 = atomicAdd(&cursor[r.y], 1);
        int p2 = atomicAdd(&cursor[r.z], 1);
        int p3 = atomicAdd(&cursor[r.w], 1);
        edge_r[p0] = make_int2(c.x, __builtin_bit_cast(int, v.x));
        edge_r[p1] = make_int2(c.y, __builtin_bit_cast(int, v.y));
        edge_r[p2] = make_int2(c.z, __builtin_bit_cast(int, v.z));
        edge_r[p3] = make_int2(c.w, __builtin_bit_cast(int, v.w));
    }
}

// ---------- gather: out[row] = relu(sum v * hb[c]), 4-way edge ILP ----------
__global__ __launch_bounds__(256) void gather_rows(const int* __restrict__ ptr,
                                                   const int2* __restrict__ edge_r,
                                                   const unsigned short* __restrict__ hb,
                                                   float* __restrict__ out) {
    int row  = blockIdx.x * 4 + (threadIdx.x >> 6);
    int lane = threadIdx.x & 63;
    if (row >= N_NODES) return;
    // row is wave-uniform -> force bounds into SGPRs (edge loads become scalar)
    int beg = __builtin_amdgcn_readfirstlane(ptr[row]);
    int end = __builtin_amdgcn_readfirstlane(ptr[row + 1]);

    float ax0 = 0.f, ay0 = 0.f, ax1 = 0.f, ay1 = 0.f;
    float ax2 = 0.f, ay2 = 0.f, ax3 = 0.f, ay3 = 0.f;
    int j = beg;
    for (; j + 4 <= end; j += 4) {
        int2 e0 = edge_r[j + 0];
        int2 e1 = edge_r[j + 1];
        int2 e2 = edge_r[j + 2];
        int2 e3 = edge_r[j + 3];
        unsigned int h0 = *(const unsigned int*)(hb + (size_t)e0.x * D_OUT + lane * 2);
        unsigned int h1 = *(const unsigned int*)(hb + (size_t)e1.x * D_OUT + lane * 2);
        unsigned int h2 = *(const unsigned int*)(hb + (size_t)e2.x * D_OUT + lane * 2);
        unsigned int h3 = *(const unsigned int*)(hb + (size_t)e3.x * D_OUT + lane * 2);
        float v0 = __builtin_bit_cast(float, e0.y);
        float v1 = __builtin_bit_cast(float, e1.y);
        float v2 = __builtin_bit_cast(float, e2.y);
        float v3 = __builtin_bit_cast(float, e3.y);
        ax0 = fmaf(v0, bf_lo(h0), ax0); ay0 = fmaf(v0, bf_hi(h0), ay0);
        ax1 = fmaf(v1, bf_lo(h1), ax1); ay1 = fmaf(v1, bf_hi(h1), ay1);
        ax2 = fmaf(v2, bf_lo(h2), ax2); ay2 = fmaf(v2, bf_hi(h2), ay2);
        ax3 = fmaf(v3, bf_lo(h3), ax3); ay3 = fmaf(v3, bf_hi(h3), ay3);
    }
    for (; j < end; ++j) {
        int2 e = edge_r[j];
        unsigned int h = *(const unsigned int*)(hb + (size_t)e.x * D_OUT + lane * 2);
        float v = __builtin_bit_cast(float, e.y);
        ax0 = fmaf(v, bf_lo(h), ax0);
        ay0 = fmaf(v, bf_hi(h), ay0);
    }
    float accx = (ax0 + ax1) + (ax2 + ax3);
    float accy = (ay0 + ay1) + (ay2 + ay3);
    float2 o = make_float2(fmaxf(accx, 0.f), fmaxf(accy, 0.f));
    *(float2*)(out + (size_t)row * D_OUT + lane * 2) = o;
}

extern "C" void kernel_launch(void* const* d_in, const int* in_sizes, int n_in,
                              void* d_out, int out_size, void* d_ws, size_t ws_size,
                              hipStream_t stream) {
    const float* x    = (const float*)d_in[0];
    const float* W    = (const float*)d_in[1];
    const int*   rows = (const int*)d_in[2];
    const int*   cols = (const int*)d_in[3];
    const float* vals = (const float*)d_in[4];
    float* out = (float*)d_out;

    // workspace layout (~39.3 MB)
    char* ws = (char*)d_ws;
    size_t off = 0;
    unsigned short* hb  = (unsigned short*)(ws + off); off += ((size_t)N_NODES * D_OUT * 2 + 255) & ~(size_t)255;
    unsigned short* WbT = (unsigned short*)(ws + off); off += ((size_t)D_IN * D_OUT * 2 + 255) & ~(size_t)255;
    int*  ptr    = (int*)(ws + off); off += ((size_t)(N_NODES + 1) * 4 + 255) & ~(size_t)255;
    int*  cursor = (int*)(ws + off); off += ((size_t)N_NODES * 4 + 255) & ~(size_t)255;
    int2* edge_r = (int2*)(ws + off); off += ((size_t)N_EDGES * 8 + 255) & ~(size_t)255;
    int*  bsum   = (int*)(ws + off); off += 4096;

    const int nscan = (N_NODES + SCHUNK - 1) / SCHUNK;  // 98

    convert_w<<<(D_IN * D_OUT) / 256, 256, 0, stream>>>(W, WbT);
    gemm_mfma<<<(N_NODES + 127) / 128, 256, 0, stream>>>(x, WbT, hb);

    hipMemsetAsync(cursor, 0, (size_t)N_NODES * 4, stream);
    hist_rows<<<(N_EDGES / 4 + 255) / 256, 256, 0, stream>>>(rows, cursor);
    scan_reduce<<<nscan, 1024, 0, stream>>>(cursor, bsum, N_NODES);
    scan_bsums<<<1, 64, 0, stream>>>(bsum, nscan);
    scan_apply<<<nscan, 1024, 0, stream>>>(cursor, bsum, ptr, cursor, N_NODES);
    permute_edges<<<(N_EDGES / 4 + 255) / 256, 256, 0, stream>>>(rows, cols, vals, cursor, edge_r);

    gather_rows<<<(N_NODES + 3) / 4, 256, 0, stream>>>(ptr, edge_r, hb, out);
}